// Round 3
// baseline (229.527 us; speedup 1.0000x reference)
//
#include <hip/hip_runtime.h>
#include <hip/hip_bf16.h>

typedef unsigned short ushort_t;
typedef unsigned int uint_t;
typedef __attribute__((ext_vector_type(8))) short short8;
typedef __attribute__((ext_vector_type(4))) float float4v;
typedef __attribute__((ext_vector_type(4))) uint_t uint4v;

#define NLAT 2048
#define DLAT 64

// d_ws layout (ushort units): [0..127] flag area (int at byte 0), then packed weights
#define PW_BASE 128
#define PW0_OFF 0        // layer0: KT=7 -> 7*16*64*8 = 57344 ushorts
#define PW1_OFF 57344    // KT=8 -> 65536 each
#define PW2_OFF 122880
#define PW3_OFF 188416

__device__ __forceinline__ float b2f(ushort_t u) {
  union { uint_t i; float f; } v; v.i = ((uint_t)u) << 16; return v.f;
}
__device__ __forceinline__ ushort_t f2b(float f) {
  uint_t x = __float_as_uint(f);
  uint_t r = (x + 0x7fffu + ((x >> 16) & 1u)) >> 16;   // RNE
  return (ushort_t)r;
}
// HW packed f32x2 -> bf16x2 (v_cvt_pk_bf16_f32)
__device__ __forceinline__ uint_t pack2(float lo, float hi) {
  float2 t; t.x = lo; t.y = hi;
  union { __hip_bfloat162 h; uint_t u; } cv;
  cv.h = __float22bfloat162_rn(t);
  return cv.u;
}
__device__ __forceinline__ int imin(int a, int b) { return a < b ? a : b; }
__device__ __forceinline__ int imax(int a, int b) { return a > b ? a : b; }

__device__ __forceinline__ float ldv(const float* p, long i)    { return p[i]; }
__device__ __forceinline__ float ldv(const ushort_t* p, long i) { return b2f(p[i]); }
__device__ __forceinline__ void stv(float* p, long i, float v)    { p[i] = v; }
__device__ __forceinline__ void stv(ushort_t* p, long i, float v) { p[i] = f2b(v); }

__device__ __forceinline__ float4 load4f(const float* p) { return *(const float4*)p; }
__device__ __forceinline__ float4 load4f(const ushort_t* p) {
  uint2 u = *(const uint2*)p;
  float4 r;
  r.x = b2f((ushort_t)(u.x & 0xffffu)); r.y = b2f((ushort_t)(u.x >> 16));
  r.z = b2f((ushort_t)(u.y & 0xffffu)); r.w = b2f((ushort_t)(u.y >> 16));
  return r;
}

// ---------------------------------------------------------------------------
// Runtime dtype probe: flag=1 -> fp32 inputs, flag=0 -> bf16
// ---------------------------------------------------------------------------
__global__ void detect_mode(const ushort_t* __restrict__ lat, int* __restrict__ flag) {
  if (threadIdx.x == 0) *flag = 0;
  __syncthreads();
  int big = 0;
  for (int i = threadIdx.x; i < 1024; i += 64) {
    float v = b2f(lat[i]);
    if (!(fabsf(v) < 1e5f)) big = 1;
  }
  if (__any(big) && threadIdx.x == 0) *flag = 1;
}

// ---------------------------------------------------------------------------
// Pack weights as MFMA A-fragments (A = W^T, m = chan_out), sigma k-permuted
// to match the C-register order of the previous layer:
//   element j of frag(mt,kt,lane) = W[sigma][mt*16 + (lane&15)]
//   sigma = 32*kt + 16*(j>>2) + 4*(lane>>4) + (j&3)
// Layer 0: sigma indexes [sampled(192) | coord | pe(12) | pad->224].
// (unchanged — the sigma trick is reused verbatim)
// ---------------------------------------------------------------------------
template <typename TI>
__global__ void pack_w_t(const TI* __restrict__ W0, const TI* __restrict__ W1,
                         const TI* __restrict__ W2, const TI* __restrict__ W3,
                         ushort_t* __restrict__ pw, const int* __restrict__ flag, int want)
{
  if (*flag != want) return;
  int g = blockIdx.x * blockDim.x + threadIdx.x;
  if (g >= 31 * 1024) return;
  int lane = g & 63, q = lane >> 4;
  int mt   = (g >> 6) & 15;
  int ktg  = g >> 10;                       // 0..30
  const TI* W; ushort_t* dst; int kt, KT; bool isw0 = false;
  if (ktg < 7)       { W = W0; dst = pw + PW0_OFF; kt = ktg;      KT = 7; isw0 = true; }
  else if (ktg < 15) { W = W1; dst = pw + PW1_OFF; kt = ktg - 7;  KT = 8; }
  else if (ktg < 23) { W = W2; dst = pw + PW2_OFF; kt = ktg - 15; KT = 8; }
  else               { W = W3; dst = pw + PW3_OFF; kt = ktg - 23; KT = 8; }
  int col = mt * 16 + (lane & 15);
  uint_t words[4];
#pragma unroll
  for (int h = 0; h < 4; ++h) {
    ushort_t vv[2];
#pragma unroll
    for (int e = 0; e < 2; ++e) {
      int j = 2 * h + e;
      int f = 32 * kt + 16 * (j >> 2) + 4 * q + (j & 3);
      int row = f;
      if (isw0) row = (f < 192) ? (13 + f) : (f == 192 ? 0 : (f <= 204 ? f - 192 : -1));
      vv[e] = (row >= 0) ? f2b(ldv(W, (long)row * 256 + col)) : (ushort_t)0;
    }
    words[h] = (uint_t)vv[0] | ((uint_t)vv[1] << 16);
  }
  uint4 o; o.x = words[0]; o.y = words[1]; o.z = words[2]; o.w = words[3];
  *(uint4*)(dst + ((size_t)(mt * KT + kt) * 64 + lane) * 8) = o;
}

// ---------------------------------------------------------------------------
// OVERLAP RESTRUCTURE (R3): the R2 counters showed MFMA + DS + VMEM summing
// to ~100% of runtime (36% + ~30% + ~34%) — phase-serialized pipes. Fixes:
//  (1) act double-buffered in LDS (2 x 32 KB): convert writes the OTHER
//      buffer -> only ONE barrier per layer (writes-visible); waves slip.
//  (2) B-fragments register-prefetched one kt ahead (like A): the MFMA burst
//      of step kt overlaps the ds_reads + global_loads of kt+1.
//  (3) raw s_barrier + explicit lgkmcnt (no vmcnt drain) so next-layer A0
//      prefetch stays in flight across the barrier; s_setprio around MFMAs.
// acc is indexed by compile-time slot i; the per-wave pt rotation
// p = (wv+i)&3 appears only in ADDRESSES (never array indices -> no scratch).
// ---------------------------------------------------------------------------
template <int KT>
__device__ __forceinline__ void prefetch_A0(const ushort_t* __restrict__ pwl,
                                            short8 (&A0)[4], int lane, int wv)
{
  const ushort_t* abase = pwl + (((size_t)(4 * wv) * KT) * 64 + lane) * 8;
#pragma unroll
  for (int m = 0; m < 4; ++m)
    A0[m] = *(const short8*)(abase + (size_t)(m * KT) * 512);
}

template <int KT>
__device__ __forceinline__ void run_layer_new(const ushort_t* __restrict__ pwl,
                                              float4v (&acc)[4][4],
                                              const ushort_t* __restrict__ act,
                                              int lane, int wv, short8 (&A0)[4])
{
#pragma unroll
  for (int m = 0; m < 4; ++m)
#pragma unroll
    for (int i = 0; i < 4; ++i)
      acc[m][i] = (float4v){0.f, 0.f, 0.f, 0.f};

  const ushort_t* abase = pwl + (((size_t)(4 * wv) * KT) * 64 + lane) * 8;
  short8 A1[4], B0[4], B1[4];

  // slot i <-> pt-tile p=(wv+i)&3 ; offset = p*4096 + kt*512 + lane*8 ushorts
  int boff[4];
#pragma unroll
  for (int i = 0; i < 4; ++i) boff[i] = (((wv + i) & 3) << 12) + (lane << 3);

#pragma unroll
  for (int i = 0; i < 4; ++i)
    B0[i] = *(const short8*)&act[boff[i]];

#pragma unroll
  for (int kt = 0; kt < KT; ++kt) {
    short8 (&Ac)[4] = (kt & 1) ? A1 : A0;   // compile-time select (unrolled)
    short8 (&An)[4] = (kt & 1) ? A0 : A1;
    short8 (&Bc)[4] = (kt & 1) ? B1 : B0;
    short8 (&Bn)[4] = (kt & 1) ? B0 : B1;
    if (kt + 1 < KT) {
#pragma unroll
      for (int m = 0; m < 4; ++m)
        An[m] = *(const short8*)(abase + (size_t)(m * KT + kt + 1) * 512);
#pragma unroll
      for (int i = 0; i < 4; ++i)
        Bn[i] = *(const short8*)&act[boff[i] + (kt + 1) * 512];
    }
    __builtin_amdgcn_s_setprio(1);
#pragma unroll
    for (int i = 0; i < 4; ++i) {
      acc[0][i] = __builtin_amdgcn_mfma_f32_16x16x32_bf16(Ac[0], Bc[i], acc[0][i], 0, 0, 0);
      acc[1][i] = __builtin_amdgcn_mfma_f32_16x16x32_bf16(Ac[1], Bc[i], acc[1][i], 0, 0, 0);
      acc[2][i] = __builtin_amdgcn_mfma_f32_16x16x32_bf16(Ac[2], Bc[i], acc[2][i], 0, 0, 0);
      acc[3][i] = __builtin_amdgcn_mfma_f32_16x16x32_bf16(Ac[3], Bc[i], acc[3][i], 0, 0, 0);
    }
    __builtin_amdgcn_s_setprio(0);
  }
}

// acc -> bias+relu+bf16 -> actN (the OTHER act buffer; B-frags of next layer).
// kt_dst = 2wv + (mt>>1), half = mt&1, lane slot = own lane (proven mapping);
// slot i holds pt-tile p=(wv+i)&3 (address-only). Single barrier: writes to
// actN can't race reads of actC, so only writes-visible ordering is needed.
// No vmcnt drain -> caller's A0 prefetch stays in flight across the barrier.
__device__ __forceinline__ void convert_store(float4v (&acc)[4][4],
                                              ushort_t* __restrict__ actN,
                                              const float* __restrict__ bwl,
                                              int lane, int wv, int q)
{
#pragma unroll
  for (int p2 = 0; p2 < 2; ++p2) {
    const float4 bE = *(const float4*)&bwl[wv * 64 + p2 * 32 + 4 * q];
    const float4 bO = *(const float4*)&bwl[wv * 64 + p2 * 32 + 16 + 4 * q];
    const int kt = 2 * wv + p2;
#pragma unroll
    for (int i = 0; i < 4; ++i) {
      const int p = (wv + i) & 3;     // runtime, address-only
      const float4v& aE = acc[2 * p2][i];
      const float4v& aO = acc[2 * p2 + 1][i];
      uint4 o;
      o.x = pack2(fmaxf(aE[0] + bE.x, 0.f), fmaxf(aE[1] + bE.y, 0.f));
      o.y = pack2(fmaxf(aE[2] + bE.z, 0.f), fmaxf(aE[3] + bE.w, 0.f));
      o.z = pack2(fmaxf(aO[0] + bO.x, 0.f), fmaxf(aO[1] + bO.y, 0.f));
      o.w = pack2(fmaxf(aO[2] + bO.z, 0.f), fmaxf(aO[3] + bO.w, 0.f));
      *(uint4*)&actN[(size_t)(p << 12) + kt * 512 + (lane << 3)] = o;
    }
  }
  asm volatile("s_waitcnt lgkmcnt(0)" ::: "memory");
  __builtin_amdgcn_s_barrier();          // writes visible before next layer
}

// ---------------------------------------------------------------------------
// Fused kernel. 256 threads = 4 waves, 64 points/block, grid 4096.
// LDS ~70.7 KB -> 2 blocks/CU; launch_bounds(256,2) gives regalloc room for
// the A+B register double-buffers (no spill).
// ---------------------------------------------------------------------------
template <typename TI>
__global__ __launch_bounds__(256, 2) void lisa_fused_t(
    const TI* __restrict__ coord, const TI* __restrict__ latent,
    const TI* __restrict__ bias0, const TI* __restrict__ bias1,
    const TI* __restrict__ bias2, const TI* __restrict__ bias3,
    const TI* __restrict__ W4,    const TI* __restrict__ b4,
    const ushort_t* __restrict__ pw, TI* __restrict__ out,
    const int* __restrict__ flag, int want)
{
  if (*flag != want) return;
  __shared__ __align__(16) ushort_t act[2][4 * 8 * 64 * 8];  // 2 x 32 KB
  __shared__ __align__(16) float bw[4 * 256 + 256 + 1];      // biases | w4 | b4

  const int tid  = threadIdx.x;
  const int lane = tid & 63, q = lane >> 4, m15 = lane & 15;
  const int wv   = tid >> 6;                               // 0..3
  const long pbase = (long)blockIdx.x * 64 + wv * 16 + m15;

  // issue L0 A0 prefetch immediately — hides L2 latency under feature build
  short8 A0[4];
  prefetch_A0<7>(pw + PW0_OFF, A0, lane, wv);

  // ---- bias/w4 table ----
  for (int i = tid; i < 1281; i += 256) {
    float v;
    if (i < 256)       v = ldv(bias0, i);
    else if (i < 512)  v = ldv(bias1, i - 256);
    else if (i < 768)  v = ldv(bias2, i - 512);
    else if (i < 1024) v = ldv(bias3, i - 768);
    else if (i < 1280) v = ldv(W4, i - 1024);
    else               v = ldv(b4, 0);
    bw[i] = v;
  }

  // ---- feature build into sigma-ordered B-frags; wave wv owns pt-tile wv ----
  {
    const long p = pbase;
    float c   = ldv(coord, p);
    float ixv = c * 2048.0f - 0.5f;
    float x0f = floorf(ixv);
    float t   = ixv - x0f;
    int   x0  = (int)x0f;
    int   i0  = imin(imax(x0, 0), NLAT - 1);
    int   i1  = imin(imax(x0 + 1, 0), NLAT - 1);
    float w0 = 1.0f - t, w1 = t;
    int rows0[3] = { imax(i0 - 1, 0), i0, imin(i0 + 1, NLAT - 1) };
    int rows1[3] = { imax(i1 - 1, 0), i1, imin(i1 + 1, NLAT - 1) };
    const TI* lat = latent + (size_t)(p >> 15) * (NLAT * DLAT);
    uint4v hu[7];
#pragma unroll
    for (int tb = 0; tb < 12; ++tb) {
      int region = tb >> 2;
      int d0 = 16 * (tb & 3) + 4 * q;
      float4 a = load4f(lat + (long)rows0[region] * DLAT + d0);
      float4 b = load4f(lat + (long)rows1[region] * DLAT + d0);
      hu[tb >> 1][(tb & 1) * 2 + 0] = pack2(w0 * a.x + w1 * b.x, w0 * a.y + w1 * b.y);
      hu[tb >> 1][(tb & 1) * 2 + 1] = pack2(w0 * a.z + w1 * b.z, w0 * a.w + w1 * b.w);
    }
    float pv[4];
#pragma unroll
    for (int s = 0; s < 4; ++s) {
      int f = 192 + 4 * q + s;
      float v = 0.0f;
      if (f == 192) v = c;
      else if (f <= 204) {
        int i = f - 193;
        float fr = (float)(1 << (i >> 1));
        float ang = c * fr;
        v = (i & 1) ? __cosf(ang) : __sinf(ang);
      }
      pv[s] = v;
    }
    hu[6][0] = pack2(pv[0], pv[1]);
    hu[6][1] = pack2(pv[2], pv[3]);
    hu[6][2] = 0; hu[6][3] = 0;

#pragma unroll
    for (int kt = 0; kt < 7; ++kt)
      *(uint4v*)&act[0][((size_t)(wv * 8 + kt) * 64 + lane) * 8] = hu[kt];
  }
  __syncthreads();   // features + bw table ready

  float4v acc[4][4];

  run_layer_new<7>(pw + PW0_OFF, acc, act[0], lane, wv, A0);
  prefetch_A0<8>(pw + PW1_OFF, A0, lane, wv);
  convert_store(acc, act[1], bw + 0 * 256, lane, wv, q);
  run_layer_new<8>(pw + PW1_OFF, acc, act[1], lane, wv, A0);
  prefetch_A0<8>(pw + PW2_OFF, A0, lane, wv);
  convert_store(acc, act[0], bw + 1 * 256, lane, wv, q);
  run_layer_new<8>(pw + PW2_OFF, acc, act[0], lane, wv, A0);
  prefetch_A0<8>(pw + PW3_OFF, A0, lane, wv);
  convert_store(acc, act[1], bw + 2 * 256, lane, wv, q);
  run_layer_new<8>(pw + PW3_OFF, acc, act[1], lane, wv, A0);

  // ---- final: bias3+relu fused with dot against w4 (wave covers 64 chans) ----
  float psum[4] = {0.f, 0.f, 0.f, 0.f};
#pragma unroll
  for (int m = 0; m < 4; ++m) {
    const float4 b3v = *(const float4*)&bw[3 * 256 + wv * 64 + m * 16 + 4 * q];
    const float4 w4v = *(const float4*)&bw[1024 + wv * 64 + m * 16 + 4 * q];
#pragma unroll
    for (int i = 0; i < 4; ++i) {
      float v;
      v = fmaxf(acc[m][i][0] + b3v.x, 0.f); psum[i] += v * w4v.x;
      v = fmaxf(acc[m][i][1] + b3v.y, 0.f); psum[i] += v * w4v.y;
      v = fmaxf(acc[m][i][2] + b3v.z, 0.f); psum[i] += v * w4v.z;
      v = fmaxf(acc[m][i][3] + b3v.w, 0.f); psum[i] += v * w4v.w;
    }
  }
#pragma unroll
  for (int i = 0; i < 4; ++i) {
    psum[i] += __shfl_xor(psum[i], 16, 64);
    psum[i] += __shfl_xor(psum[i], 32, 64);
  }

  // act[0] is dead (last read finished before the L2-convert barrier) ->
  // overlay partials there; slot i maps to pt-tile p=(wv+i)&3 (address-only).
  float* part = (float*)act[0];      // [wv][64] partials
  if (lane < 16) {
#pragma unroll
    for (int i = 0; i < 4; ++i) {
      const int p = (wv + i) & 3;
      part[wv * 64 + p * 16 + lane] = psum[i];
    }
  }
  __syncthreads();
  if (tid < 64) {
    float s = part[tid] + part[64 + tid] + part[128 + tid] + part[192 + tid]
            + bw[1280];
    stv(out, (long)blockIdx.x * 64 + tid, s);
  }
}

extern "C" void kernel_launch(void* const* d_in, const int* in_sizes, int n_in,
                              void* d_out, int out_size, void* d_ws, size_t ws_size,
                              hipStream_t stream) {
  int* flag = (int*)d_ws;
  ushort_t* pw = (ushort_t*)d_ws + PW_BASE;

  detect_mode<<<1, 64, 0, stream>>>((const ushort_t*)d_in[1], flag);

  // fp32-input variant (flag==1)
  pack_w_t<float><<<62, 512, 0, stream>>>(
      (const float*)d_in[2], (const float*)d_in[4], (const float*)d_in[6],
      (const float*)d_in[8], pw, flag, 1);
  lisa_fused_t<float><<<4096, 256, 0, stream>>>(
      (const float*)d_in[0], (const float*)d_in[1],
      (const float*)d_in[3], (const float*)d_in[5], (const float*)d_in[7],
      (const float*)d_in[9], (const float*)d_in[10], (const float*)d_in[11],
      pw, (float*)d_out, flag, 1);

  // bf16-input variant (flag==0)
  pack_w_t<ushort_t><<<62, 512, 0, stream>>>(
      (const ushort_t*)d_in[2], (const ushort_t*)d_in[4], (const ushort_t*)d_in[6],
      (const ushort_t*)d_in[8], pw, flag, 0);
  lisa_fused_t<ushort_t><<<4096, 256, 0, stream>>>(
      (const ushort_t*)d_in[0], (const ushort_t*)d_in[1],
      (const ushort_t*)d_in[3], (const ushort_t*)d_in[5], (const ushort_t*)d_in[7],
      (const ushort_t*)d_in[9], (const ushort_t*)d_in[10], (const ushort_t*)d_in[11],
      pw, (ushort_t*)d_out, flag, 0);
}

// Round 5
// 228.213 us; speedup vs baseline: 1.0058x; 1.0058x over previous
//
#include <hip/hip_runtime.h>
#include <hip/hip_bf16.h>

typedef unsigned short ushort_t;
typedef unsigned int uint_t;
typedef __attribute__((ext_vector_type(8))) short short8;
typedef __attribute__((ext_vector_type(4))) float float4v;
typedef __attribute__((ext_vector_type(4))) uint_t uint4v;

#define NLAT 2048
#define DLAT 64

// d_ws layout (ushort units): [0..127] flag area (int at byte 0), then packed weights
#define PW_BASE 128
#define PW0_OFF 0        // layer0: KT=7 -> 7*16*64*8 = 57344 ushorts
#define PW1_OFF 57344    // KT=8 -> 65536 each
#define PW2_OFF 122880
#define PW3_OFF 188416

__device__ __forceinline__ float b2f(ushort_t u) {
  union { uint_t i; float f; } v; v.i = ((uint_t)u) << 16; return v.f;
}
__device__ __forceinline__ ushort_t f2b(float f) {
  uint_t x = __float_as_uint(f);
  uint_t r = (x + 0x7fffu + ((x >> 16) & 1u)) >> 16;   // RNE
  return (ushort_t)r;
}
// HW packed f32x2 -> bf16x2 (v_cvt_pk_bf16_f32)
__device__ __forceinline__ uint_t pack2(float lo, float hi) {
  float2 t; t.x = lo; t.y = hi;
  union { __hip_bfloat162 h; uint_t u; } cv;
  cv.h = __float22bfloat162_rn(t);
  return cv.u;
}
__device__ __forceinline__ int imin(int a, int b) { return a < b ? a : b; }
__device__ __forceinline__ int imax(int a, int b) { return a > b ? a : b; }

__device__ __forceinline__ float ldv(const float* p, long i)    { return p[i]; }
__device__ __forceinline__ float ldv(const ushort_t* p, long i) { return b2f(p[i]); }
__device__ __forceinline__ void stv(float* p, long i, float v)    { p[i] = v; }
__device__ __forceinline__ void stv(ushort_t* p, long i, float v) { p[i] = f2b(v); }

__device__ __forceinline__ float4 load4f(const float* p) { return *(const float4*)p; }
__device__ __forceinline__ float4 load4f(const ushort_t* p) {
  uint2 u = *(const uint2*)p;
  float4 r;
  r.x = b2f((ushort_t)(u.x & 0xffffu)); r.y = b2f((ushort_t)(u.x >> 16));
  r.z = b2f((ushort_t)(u.y & 0xffffu)); r.w = b2f((ushort_t)(u.y >> 16));
  return r;
}

// ---------------------------------------------------------------------------
// Runtime dtype probe: flag=1 -> fp32 inputs, flag=0 -> bf16
// ---------------------------------------------------------------------------
__global__ void detect_mode(const ushort_t* __restrict__ lat, int* __restrict__ flag) {
  if (threadIdx.x == 0) *flag = 0;
  __syncthreads();
  int big = 0;
  for (int i = threadIdx.x; i < 1024; i += 64) {
    float v = b2f(lat[i]);
    if (!(fabsf(v) < 1e5f)) big = 1;
  }
  if (__any(big) && threadIdx.x == 0) *flag = 1;
}

// ---------------------------------------------------------------------------
// Pack weights as MFMA A-fragments (A = W^T, m = chan_out), sigma k-permuted
// to match the C-register order of the previous layer:
//   element j of frag(mt,kt,lane) = W[sigma][mt*16 + (lane&15)]
//   sigma = 32*kt + 16*(j>>2) + 4*(lane>>4) + (j&3)
// Layer 0: sigma indexes [sampled(192) | coord | pe(12) | pad->224].
// (unchanged — the sigma trick is reused verbatim)
// ---------------------------------------------------------------------------
template <typename TI>
__global__ void pack_w_t(const TI* __restrict__ W0, const TI* __restrict__ W1,
                         const TI* __restrict__ W2, const TI* __restrict__ W3,
                         ushort_t* __restrict__ pw, const int* __restrict__ flag, int want)
{
  if (*flag != want) return;
  int g = blockIdx.x * blockDim.x + threadIdx.x;
  if (g >= 31 * 1024) return;
  int lane = g & 63, q = lane >> 4;
  int mt   = (g >> 6) & 15;
  int ktg  = g >> 10;                       // 0..30
  const TI* W; ushort_t* dst; int kt, KT; bool isw0 = false;
  if (ktg < 7)       { W = W0; dst = pw + PW0_OFF; kt = ktg;      KT = 7; isw0 = true; }
  else if (ktg < 15) { W = W1; dst = pw + PW1_OFF; kt = ktg - 7;  KT = 8; }
  else if (ktg < 23) { W = W2; dst = pw + PW2_OFF; kt = ktg - 15; KT = 8; }
  else               { W = W3; dst = pw + PW3_OFF; kt = ktg - 23; KT = 8; }
  int col = mt * 16 + (lane & 15);
  uint_t words[4];
#pragma unroll
  for (int h = 0; h < 4; ++h) {
    ushort_t vv[2];
#pragma unroll
    for (int e = 0; e < 2; ++e) {
      int j = 2 * h + e;
      int f = 32 * kt + 16 * (j >> 2) + 4 * q + (j & 3);
      int row = f;
      if (isw0) row = (f < 192) ? (13 + f) : (f == 192 ? 0 : (f <= 204 ? f - 192 : -1));
      vv[e] = (row >= 0) ? f2b(ldv(W, (long)row * 256 + col)) : (ushort_t)0;
    }
    words[h] = (uint_t)vv[0] | ((uint_t)vv[1] << 16);
  }
  uint4 o; o.x = words[0]; o.y = words[1]; o.z = words[2]; o.w = words[3];
  *(uint4*)(dst + ((size_t)(mt * KT + kt) * 64 + lane) * 8) = o;
}

// ---------------------------------------------------------------------------
// R4 (resubmit after infra failure): DEEP A-PREFETCH. R0-R3 all stalled every
// kt on vmcnt for the weight stream (prefetch distance 1 kt ~ 310 cy <
// L2-under-load latency 500-900cy), serializing MFMA+DS+VMEM into a sum.
// Fix: 4-slot register ring, loads issued 3 kt (>=900 cy) ahead. At iteration
// kt: issue loads for kt+3 into slot (kt+3)&3 (!= current slot; last consumed
// 1 iter ago), then MFMA on slot kt&3. In-order vmem return => compiler's
// vmcnt wait is satisfied by loads issued ~3 MFMA-bursts earlier. Next
// layer's slots 0..2 are issued BEFORE convert+barrier (raw barrier, no vmcnt
// drain) to hide one more latency under convert VALU. All indices
// compile-time (full unroll).
// ---------------------------------------------------------------------------
template <int KT>
__device__ __forceinline__ void prefetch_A3(const ushort_t* __restrict__ pwl,
                                            short8 (&Ar)[4][4], int lane, int wv)
{
  const ushort_t* abase = pwl + (((size_t)(4 * wv) * KT) * 64 + lane) * 8;
#pragma unroll
  for (int s = 0; s < 3; ++s)
#pragma unroll
    for (int m = 0; m < 4; ++m)
      Ar[s][m] = *(const short8*)(abase + (size_t)(m * KT + s) * 512);
}

template <int KT>
__device__ __forceinline__ void run_layer_new(const ushort_t* __restrict__ pwl,
                                              float4v (&acc)[4][4],
                                              const ushort_t* __restrict__ act,
                                              int lane, int wv, short8 (&Ar)[4][4])
{
#pragma unroll
  for (int m = 0; m < 4; ++m)
#pragma unroll
    for (int i = 0; i < 4; ++i)
      acc[m][i] = (float4v){0.f, 0.f, 0.f, 0.f};

  const ushort_t* abase = pwl + (((size_t)(4 * wv) * KT) * 64 + lane) * 8;
  short8 B0[4], B1[4];

  // slot i <-> pt-tile p=(wv+i)&3 ; offset = p*4096 + kt*512 + lane*8 ushorts
  int boff[4];
#pragma unroll
  for (int i = 0; i < 4; ++i) boff[i] = (((wv + i) & 3) << 12) + (lane << 3);

#pragma unroll
  for (int i = 0; i < 4; ++i)
    B0[i] = *(const short8*)&act[boff[i]];

#pragma unroll
  for (int kt = 0; kt < KT; ++kt) {
    short8 (&Bc)[4] = (kt & 1) ? B1 : B0;   // compile-time select (unrolled)
    short8 (&Bn)[4] = (kt & 1) ? B0 : B1;
    // A-ring: issue loads for kt+3 into slot (kt+3)&3 (3-deep prefetch)
    if (kt + 3 < KT) {
#pragma unroll
      for (int m = 0; m < 4; ++m)
        Ar[(kt + 3) & 3][m] =
            *(const short8*)(abase + (size_t)(m * KT + kt + 3) * 512);
    }
    // B: 1-deep prefetch (DS latency ~120-200 cy << one MFMA burst)
    if (kt + 1 < KT) {
#pragma unroll
      for (int i = 0; i < 4; ++i)
        Bn[i] = *(const short8*)&act[boff[i] + (kt + 1) * 512];
    }
    __builtin_amdgcn_s_setprio(1);
#pragma unroll
    for (int i = 0; i < 4; ++i) {
      acc[0][i] = __builtin_amdgcn_mfma_f32_16x16x32_bf16(Ar[kt & 3][0], Bc[i], acc[0][i], 0, 0, 0);
      acc[1][i] = __builtin_amdgcn_mfma_f32_16x16x32_bf16(Ar[kt & 3][1], Bc[i], acc[1][i], 0, 0, 0);
      acc[2][i] = __builtin_amdgcn_mfma_f32_16x16x32_bf16(Ar[kt & 3][2], Bc[i], acc[2][i], 0, 0, 0);
      acc[3][i] = __builtin_amdgcn_mfma_f32_16x16x32_bf16(Ar[kt & 3][3], Bc[i], acc[3][i], 0, 0, 0);
    }
    __builtin_amdgcn_s_setprio(0);
  }
}

// acc -> bias+relu+bf16 -> actN (the OTHER act buffer; B-frags of next layer).
// kt_dst = 2wv + (mt>>1), half = mt&1, lane slot = own lane (proven mapping);
// slot i holds pt-tile p=(wv+i)&3 (address-only). Single barrier (dbuf act).
// No vmcnt drain -> caller's A-ring prefetch stays in flight across it.
__device__ __forceinline__ void convert_store(float4v (&acc)[4][4],
                                              ushort_t* __restrict__ actN,
                                              const float* __restrict__ bwl,
                                              int lane, int wv, int q)
{
#pragma unroll
  for (int p2 = 0; p2 < 2; ++p2) {
    const float4 bE = *(const float4*)&bwl[wv * 64 + p2 * 32 + 4 * q];
    const float4 bO = *(const float4*)&bwl[wv * 64 + p2 * 32 + 16 + 4 * q];
    const int kt = 2 * wv + p2;
#pragma unroll
    for (int i = 0; i < 4; ++i) {
      const int p = (wv + i) & 3;     // runtime, address-only
      const float4v& aE = acc[2 * p2][i];
      const float4v& aO = acc[2 * p2 + 1][i];
      uint4 o;
      o.x = pack2(fmaxf(aE[0] + bE.x, 0.f), fmaxf(aE[1] + bE.y, 0.f));
      o.y = pack2(fmaxf(aE[2] + bE.z, 0.f), fmaxf(aE[3] + bE.w, 0.f));
      o.z = pack2(fmaxf(aO[0] + bO.x, 0.f), fmaxf(aO[1] + bO.y, 0.f));
      o.w = pack2(fmaxf(aO[2] + bO.z, 0.f), fmaxf(aO[3] + bO.w, 0.f));
      *(uint4*)&actN[(size_t)(p << 12) + kt * 512 + (lane << 3)] = o;
    }
  }
  asm volatile("s_waitcnt lgkmcnt(0)" ::: "memory");
  __builtin_amdgcn_s_barrier();          // writes visible before next layer
}

// ---------------------------------------------------------------------------
// Fused kernel. 256 threads = 4 waves, 64 points/block, grid 4096.
// LDS ~70.7 KB -> 2 blocks/CU; VGPR ~200 (acc 64 + A-ring 64 + B 32 + misc)
// -> 2 waves/SIMD (R2 proved >2 waves buys nothing; depth does).
// ---------------------------------------------------------------------------
template <typename TI>
__global__ __launch_bounds__(256, 2) void lisa_fused_t(
    const TI* __restrict__ coord, const TI* __restrict__ latent,
    const TI* __restrict__ bias0, const TI* __restrict__ bias1,
    const TI* __restrict__ bias2, const TI* __restrict__ bias3,
    const TI* __restrict__ W4,    const TI* __restrict__ b4,
    const ushort_t* __restrict__ pw, TI* __restrict__ out,
    const int* __restrict__ flag, int want)
{
  if (*flag != want) return;
  __shared__ __align__(16) ushort_t act[2][4 * 8 * 64 * 8];  // 2 x 32 KB
  __shared__ __align__(16) float bw[4 * 256 + 256 + 1];      // biases | w4 | b4

  const int tid  = threadIdx.x;
  const int lane = tid & 63, q = lane >> 4, m15 = lane & 15;
  const int wv   = tid >> 6;                               // 0..3
  const long pbase = (long)blockIdx.x * 64 + wv * 16 + m15;

  // issue L0 A-ring prefetch (3 kt deep) immediately — hides under feat build
  short8 Ar[4][4];
  prefetch_A3<7>(pw + PW0_OFF, Ar, lane, wv);

  // ---- bias/w4 table ----
  for (int i = tid; i < 1281; i += 256) {
    float v;
    if (i < 256)       v = ldv(bias0, i);
    else if (i < 512)  v = ldv(bias1, i - 256);
    else if (i < 768)  v = ldv(bias2, i - 512);
    else if (i < 1024) v = ldv(bias3, i - 768);
    else if (i < 1280) v = ldv(W4, i - 1024);
    else               v = ldv(b4, 0);
    bw[i] = v;
  }

  // ---- feature build into sigma-ordered B-frags; wave wv owns pt-tile wv ----
  {
    const long p = pbase;
    float c   = ldv(coord, p);
    float ixv = c * 2048.0f - 0.5f;
    float x0f = floorf(ixv);
    float t   = ixv - x0f;
    int   x0  = (int)x0f;
    int   i0  = imin(imax(x0, 0), NLAT - 1);
    int   i1  = imin(imax(x0 + 1, 0), NLAT - 1);
    float w0 = 1.0f - t, w1 = t;
    int rows0[3] = { imax(i0 - 1, 0), i0, imin(i0 + 1, NLAT - 1) };
    int rows1[3] = { imax(i1 - 1, 0), i1, imin(i1 + 1, NLAT - 1) };
    const TI* lat = latent + (size_t)(p >> 15) * (NLAT * DLAT);
    uint4v hu[7];
#pragma unroll
    for (int tb = 0; tb < 12; ++tb) {
      int region = tb >> 2;
      int d0 = 16 * (tb & 3) + 4 * q;
      float4 a = load4f(lat + (long)rows0[region] * DLAT + d0);
      float4 b = load4f(lat + (long)rows1[region] * DLAT + d0);
      hu[tb >> 1][(tb & 1) * 2 + 0] = pack2(w0 * a.x + w1 * b.x, w0 * a.y + w1 * b.y);
      hu[tb >> 1][(tb & 1) * 2 + 1] = pack2(w0 * a.z + w1 * b.z, w0 * a.w + w1 * b.w);
    }
    float pv[4];
#pragma unroll
    for (int s = 0; s < 4; ++s) {
      int f = 192 + 4 * q + s;
      float v = 0.0f;
      if (f == 192) v = c;
      else if (f <= 204) {
        int i = f - 193;
        float fr = (float)(1 << (i >> 1));
        float ang = c * fr;
        v = (i & 1) ? __cosf(ang) : __sinf(ang);
      }
      pv[s] = v;
    }
    hu[6][0] = pack2(pv[0], pv[1]);
    hu[6][1] = pack2(pv[2], pv[3]);
    hu[6][2] = 0; hu[6][3] = 0;

#pragma unroll
    for (int kt = 0; kt < 7; ++kt)
      *(uint4v*)&act[0][((size_t)(wv * 8 + kt) * 64 + lane) * 8] = hu[kt];
  }
  __syncthreads();   // features + bw table ready

  float4v acc[4][4];

  run_layer_new<7>(pw + PW0_OFF, acc, act[0], lane, wv, Ar);
  prefetch_A3<8>(pw + PW1_OFF, Ar, lane, wv);
  convert_store(acc, act[1], bw + 0 * 256, lane, wv, q);
  run_layer_new<8>(pw + PW1_OFF, acc, act[1], lane, wv, Ar);
  prefetch_A3<8>(pw + PW2_OFF, Ar, lane, wv);
  convert_store(acc, act[0], bw + 1 * 256, lane, wv, q);
  run_layer_new<8>(pw + PW2_OFF, acc, act[0], lane, wv, Ar);
  prefetch_A3<8>(pw + PW3_OFF, Ar, lane, wv);
  convert_store(acc, act[1], bw + 2 * 256, lane, wv, q);
  run_layer_new<8>(pw + PW3_OFF, acc, act[1], lane, wv, Ar);

  // ---- final: bias3+relu fused with dot against w4 (wave covers 64 chans) ----
  float psum[4] = {0.f, 0.f, 0.f, 0.f};
#pragma unroll
  for (int m = 0; m < 4; ++m) {
    const float4 b3v = *(const float4*)&bw[3 * 256 + wv * 64 + m * 16 + 4 * q];
    const float4 w4v = *(const float4*)&bw[1024 + wv * 64 + m * 16 + 4 * q];
#pragma unroll
    for (int i = 0; i < 4; ++i) {
      float v;
      v = fmaxf(acc[m][i][0] + b3v.x, 0.f); psum[i] += v * w4v.x;
      v = fmaxf(acc[m][i][1] + b3v.y, 0.f); psum[i] += v * w4v.y;
      v = fmaxf(acc[m][i][2] + b3v.z, 0.f); psum[i] += v * w4v.z;
      v = fmaxf(acc[m][i][3] + b3v.w, 0.f); psum[i] += v * w4v.w;
    }
  }
#pragma unroll
  for (int i = 0; i < 4; ++i) {
    psum[i] += __shfl_xor(psum[i], 16, 64);
    psum[i] += __shfl_xor(psum[i], 32, 64);
  }

  // act[0] is dead -> overlay partials; slot i -> pt p=(wv+i)&3 (address-only)
  float* part = (float*)act[0];      // [wv][64] partials
  if (lane < 16) {
#pragma unroll
    for (int i = 0; i < 4; ++i) {
      const int p = (wv + i) & 3;
      part[wv * 64 + p * 16 + lane] = psum[i];
    }
  }
  __syncthreads();
  if (tid < 64) {
    float s = part[tid] + part[64 + tid] + part[128 + tid] + part[192 + tid]
            + bw[1280];
    stv(out, (long)blockIdx.x * 64 + tid, s);
  }
}

extern "C" void kernel_launch(void* const* d_in, const int* in_sizes, int n_in,
                              void* d_out, int out_size, void* d_ws, size_t ws_size,
                              hipStream_t stream) {
  int* flag = (int*)d_ws;
  ushort_t* pw = (ushort_t*)d_ws + PW_BASE;

  detect_mode<<<1, 64, 0, stream>>>((const ushort_t*)d_in[1], flag);

  // fp32-input variant (flag==1)
  pack_w_t<float><<<62, 512, 0, stream>>>(
      (const float*)d_in[2], (const float*)d_in[4], (const float*)d_in[6],
      (const float*)d_in[8], pw, flag, 1);
  lisa_fused_t<float><<<4096, 256, 0, stream>>>(
      (const float*)d_in[0], (const float*)d_in[1],
      (const float*)d_in[3], (const float*)d_in[5], (const float*)d_in[7],
      (const float*)d_in[9], (const float*)d_in[10], (const float*)d_in[11],
      pw, (float*)d_out, flag, 1);

  // bf16-input variant (flag==0)
  pack_w_t<ushort_t><<<62, 512, 0, stream>>>(
      (const ushort_t*)d_in[2], (const ushort_t*)d_in[4], (const ushort_t*)d_in[6],
      (const ushort_t*)d_in[8], pw, flag, 0);
  lisa_fused_t<ushort_t><<<4096, 256, 0, stream>>>(
      (const ushort_t*)d_in[0], (const ushort_t*)d_in[1],
      (const ushort_t*)d_in[3], (const ushort_t*)d_in[5], (const ushort_t*)d_in[7],
      (const ushort_t*)d_in[9], (const ushort_t*)d_in[10], (const ushort_t*)d_in[11],
      pw, (ushort_t*)d_out, flag, 0);
}

// Round 6
// 226.832 us; speedup vs baseline: 1.0119x; 1.0061x over previous
//
#include <hip/hip_runtime.h>
#include <hip/hip_bf16.h>

typedef unsigned short ushort_t;
typedef unsigned int uint_t;
typedef __attribute__((ext_vector_type(8))) short short8;
typedef __attribute__((ext_vector_type(4))) float float4v;
typedef __attribute__((ext_vector_type(4))) uint_t uint4v;

#define NLAT 2048
#define DLAT 64

// d_ws layout (ushort units): [0..127] flag area (int at byte 0), then packed weights
#define PW_BASE 128
#define PW0_OFF 0        // layer0: KT=7 -> 7*16*64*8 = 57344 ushorts
#define PW1_OFF 57344    // KT=8 -> 65536 each
#define PW2_OFF 122880
#define PW3_OFF 188416

__device__ __forceinline__ float b2f(ushort_t u) {
  union { uint_t i; float f; } v; v.i = ((uint_t)u) << 16; return v.f;
}
__device__ __forceinline__ ushort_t f2b(float f) {
  uint_t x = __float_as_uint(f);
  uint_t r = (x + 0x7fffu + ((x >> 16) & 1u)) >> 16;   // RNE
  return (ushort_t)r;
}
// HW packed f32x2 -> bf16x2 (v_cvt_pk_bf16_f32)
__device__ __forceinline__ uint_t pack2(float lo, float hi) {
  float2 t; t.x = lo; t.y = hi;
  union { __hip_bfloat162 h; uint_t u; } cv;
  cv.h = __float22bfloat162_rn(t);
  return cv.u;
}
__device__ __forceinline__ int imin(int a, int b) { return a < b ? a : b; }
__device__ __forceinline__ int imax(int a, int b) { return a > b ? a : b; }

__device__ __forceinline__ float ldv(const float* p, long i)    { return p[i]; }
__device__ __forceinline__ float ldv(const ushort_t* p, long i) { return b2f(p[i]); }
__device__ __forceinline__ void stv(float* p, long i, float v)    { p[i] = v; }
__device__ __forceinline__ void stv(ushort_t* p, long i, float v) { p[i] = f2b(v); }

__device__ __forceinline__ float4 load4f(const float* p) { return *(const float4*)p; }
__device__ __forceinline__ float4 load4f(const ushort_t* p) {
  uint2 u = *(const uint2*)p;
  float4 r;
  r.x = b2f((ushort_t)(u.x & 0xffffu)); r.y = b2f((ushort_t)(u.x >> 16));
  r.z = b2f((ushort_t)(u.y & 0xffffu)); r.w = b2f((ushort_t)(u.y >> 16));
  return r;
}

// --- forced-schedule primitives ---------------------------------------------
// Volatile asm load: the compiler CANNOT sink/collapse these (they stay in
// program order among volatile asm). No "memory" clobber: independent of all
// C++-visible memory in the K-loop (pw is read-only), so DS ops may still be
// scheduled around freely.
__device__ __forceinline__ void aload(short8& dst, const ushort_t* a) {
  asm volatile("global_load_dwordx4 %0, %1, off" : "=v"(dst) : "v"(a));
}
// Counted wait + scheduling fence. Rule #18: sched_barrier(0) right after the
// wait, else hipcc hoists register-only MFMAs above the inline-asm waitcnt.
template <int N>
__device__ __forceinline__ void vmwait() {
  if constexpr (N == 0)      asm volatile("s_waitcnt vmcnt(0)" ::: "memory");
  else if constexpr (N == 4) asm volatile("s_waitcnt vmcnt(4)" ::: "memory");
  else                       asm volatile("s_waitcnt vmcnt(8)" ::: "memory");
  __builtin_amdgcn_sched_barrier(0);
}

// ---------------------------------------------------------------------------
// Runtime dtype probe: flag=1 -> fp32 inputs, flag=0 -> bf16
// ---------------------------------------------------------------------------
__global__ void detect_mode(const ushort_t* __restrict__ lat, int* __restrict__ flag) {
  if (threadIdx.x == 0) *flag = 0;
  __syncthreads();
  int big = 0;
  for (int i = threadIdx.x; i < 1024; i += 64) {
    float v = b2f(lat[i]);
    if (!(fabsf(v) < 1e5f)) big = 1;
  }
  if (__any(big) && threadIdx.x == 0) *flag = 1;
}

// ---------------------------------------------------------------------------
// Pack weights as MFMA A-fragments (A = W^T, m = chan_out), sigma k-permuted
// to match the C-register order of the previous layer:
//   element j of frag(mt,kt,lane) = W[sigma][mt*16 + (lane&15)]
//   sigma = 32*kt + 16*(j>>2) + 4*(lane>>4) + (j&3)
// Layer 0: sigma indexes [sampled(192) | coord | pe(12) | pad->224].
// (unchanged — the sigma trick is reused verbatim)
// ---------------------------------------------------------------------------
template <typename TI>
__global__ void pack_w_t(const TI* __restrict__ W0, const TI* __restrict__ W1,
                         const TI* __restrict__ W2, const TI* __restrict__ W3,
                         ushort_t* __restrict__ pw, const int* __restrict__ flag, int want)
{
  if (*flag != want) return;
  int g = blockIdx.x * blockDim.x + threadIdx.x;
  if (g >= 31 * 1024) return;
  int lane = g & 63, q = lane >> 4;
  int mt   = (g >> 6) & 15;
  int ktg  = g >> 10;                       // 0..30
  const TI* W; ushort_t* dst; int kt, KT; bool isw0 = false;
  if (ktg < 7)       { W = W0; dst = pw + PW0_OFF; kt = ktg;      KT = 7; isw0 = true; }
  else if (ktg < 15) { W = W1; dst = pw + PW1_OFF; kt = ktg - 7;  KT = 8; }
  else if (ktg < 23) { W = W2; dst = pw + PW2_OFF; kt = ktg - 15; KT = 8; }
  else               { W = W3; dst = pw + PW3_OFF; kt = ktg - 23; KT = 8; }
  int col = mt * 16 + (lane & 15);
  uint_t words[4];
#pragma unroll
  for (int h = 0; h < 4; ++h) {
    ushort_t vv[2];
#pragma unroll
    for (int e = 0; e < 2; ++e) {
      int j = 2 * h + e;
      int f = 32 * kt + 16 * (j >> 2) + 4 * q + (j & 3);
      int row = f;
      if (isw0) row = (f < 192) ? (13 + f) : (f == 192 ? 0 : (f <= 204 ? f - 192 : -1));
      vv[e] = (row >= 0) ? f2b(ldv(W, (long)row * 256 + col)) : (ushort_t)0;
    }
    words[h] = (uint_t)vv[0] | ((uint_t)vv[1] << 16);
  }
  uint4 o; o.x = words[0]; o.y = words[1]; o.z = words[2]; o.w = words[3];
  *(uint4*)(dst + ((size_t)(mt * KT + kt) * 64 + lane) * 8) = o;
}

// ---------------------------------------------------------------------------
// R6: ASM-FORCED PIPELINE. R5's counters (VGPR=96 vs ~200 expected) proved
// hipcc collapsed every source-level prefetch and re-serialized the loop
// (5 structures -> same 35% MfmaUtil). Here the weight stream is issued via
// volatile-asm global_load_dwordx4 into a 4-slot register ring, 2 kt ahead,
// with hand-counted s_waitcnt vmcnt(8) + sched_barrier(0) before each MFMA
// burst. vmcnt audit (per wave, in-order returns; 4 loads per kt-slot):
//   entering step kt: 8 in flight (kt, kt+1)
//   issue kt+2 (or next layer's kt0/kt1 at the tail) -> 12
//   vmcnt(8) retires exactly slot kt's 4 -> MFMA on it
//   last layer tail: no issue -> vmcnt(4), then vmcnt(0).
// Convert barriers stay raw s_barrier + lgkmcnt(0) only: the 8 in-flight
// loads CROSS the layer boundary un-drained (T3/T4 pattern).
// Slot index = global step counter mod 4; BASE per layer = 0,3,3,3
// (base' = (base+KT)&3) — all compile-time under full unroll.
// ---------------------------------------------------------------------------
template <int KT>
__device__ __forceinline__ void issueA(const ushort_t* __restrict__ pwl,
                                       short8 (&dst)[4], int kt, int lane, int wv)
{
  const ushort_t* abase = pwl + (((size_t)(4 * wv) * KT) * 64 + lane) * 8;
#pragma unroll
  for (int m = 0; m < 4; ++m)
    aload(dst[m], abase + (size_t)(m * KT + kt) * 512);
}

template <int KT, int BASE, int NEXTKT>
__device__ __forceinline__ void run_layer_asm(const ushort_t* __restrict__ pwl,
                                              const ushort_t* __restrict__ pwl_next,
                                              float4v (&acc)[4][4],
                                              const ushort_t* __restrict__ act,
                                              int lane, int wv, short8 (&Ar)[4][4])
{
#pragma unroll
  for (int m = 0; m < 4; ++m)
#pragma unroll
    for (int i = 0; i < 4; ++i)
      acc[m][i] = (float4v){0.f, 0.f, 0.f, 0.f};

  short8 B0[4], B1[4];
  // slot i <-> pt-tile p=(wv+i)&3 ; offset = p*4096 + kt*512 + lane*8 ushorts
  int boff[4];
#pragma unroll
  for (int i = 0; i < 4; ++i) boff[i] = (((wv + i) & 3) << 12) + (lane << 3);
#pragma unroll
  for (int i = 0; i < 4; ++i)
    B0[i] = *(const short8*)&act[boff[i]];

#pragma unroll
  for (int kt = 0; kt < KT; ++kt) {
    // ---- issue A for step kt+2 (this layer, or next layer's kt0/kt1) ----
    if (kt + 2 < KT) {
      issueA<KT>(pwl, Ar[(BASE + kt + 2) & 3], kt + 2, lane, wv);
    } else {
      if constexpr (NEXTKT > 0)
        issueA<NEXTKT>(pwl_next, Ar[(BASE + kt + 2) & 3], kt + 2 - KT, lane, wv);
    }
    // ---- B: 1-deep C++ dbuf (compiler's fine-grained lgkmcnt is fine) ----
    short8 (&Bc)[4] = (kt & 1) ? B1 : B0;
    short8 (&Bn)[4] = (kt & 1) ? B0 : B1;
    if (kt + 1 < KT) {
#pragma unroll
      for (int i = 0; i < 4; ++i)
        Bn[i] = *(const short8*)&act[boff[i] + (kt + 1) * 512];
    }
    // ---- counted wait: slot kt's 4 loads retired, rest stay in flight ----
    if (kt + 2 < KT || NEXTKT > 0) vmwait<8>();
    else if (kt + 1 < KT)          vmwait<4>();
    else                           vmwait<0>();
    // ---- MFMA burst on slot kt ----
    short8 (&Ac)[4] = Ar[(BASE + kt) & 3];
    __builtin_amdgcn_s_setprio(1);
#pragma unroll
    for (int i = 0; i < 4; ++i) {
      acc[0][i] = __builtin_amdgcn_mfma_f32_16x16x32_bf16(Ac[0], Bc[i], acc[0][i], 0, 0, 0);
      acc[1][i] = __builtin_amdgcn_mfma_f32_16x16x32_bf16(Ac[1], Bc[i], acc[1][i], 0, 0, 0);
      acc[2][i] = __builtin_amdgcn_mfma_f32_16x16x32_bf16(Ac[2], Bc[i], acc[2][i], 0, 0, 0);
      acc[3][i] = __builtin_amdgcn_mfma_f32_16x16x32_bf16(Ac[3], Bc[i], acc[3][i], 0, 0, 0);
    }
    __builtin_amdgcn_s_setprio(0);
  }
}

// acc -> bias+relu+bf16 -> actN (the OTHER act buffer; B-frags of next layer).
// kt_dst = 2wv + (mt>>1), half = mt&1, lane slot = own lane (proven mapping);
// slot i holds pt-tile p=(wv+i)&3 (address-only). Single barrier (dbuf act).
// lgkmcnt(0) only — NO vmcnt drain: the A-ring loads stay in flight across.
__device__ __forceinline__ void convert_store(float4v (&acc)[4][4],
                                              ushort_t* __restrict__ actN,
                                              const float* __restrict__ bwl,
                                              int lane, int wv, int q)
{
#pragma unroll
  for (int p2 = 0; p2 < 2; ++p2) {
    const float4 bE = *(const float4*)&bwl[wv * 64 + p2 * 32 + 4 * q];
    const float4 bO = *(const float4*)&bwl[wv * 64 + p2 * 32 + 16 + 4 * q];
    const int kt = 2 * wv + p2;
#pragma unroll
    for (int i = 0; i < 4; ++i) {
      const int p = (wv + i) & 3;     // runtime, address-only
      const float4v& aE = acc[2 * p2][i];
      const float4v& aO = acc[2 * p2 + 1][i];
      uint4 o;
      o.x = pack2(fmaxf(aE[0] + bE.x, 0.f), fmaxf(aE[1] + bE.y, 0.f));
      o.y = pack2(fmaxf(aE[2] + bE.z, 0.f), fmaxf(aE[3] + bE.w, 0.f));
      o.z = pack2(fmaxf(aO[0] + bO.x, 0.f), fmaxf(aO[1] + bO.y, 0.f));
      o.w = pack2(fmaxf(aO[2] + bO.z, 0.f), fmaxf(aO[3] + bO.w, 0.f));
      *(uint4*)&actN[(size_t)(p << 12) + kt * 512 + (lane << 3)] = o;
    }
  }
  asm volatile("s_waitcnt lgkmcnt(0)" ::: "memory");
  __builtin_amdgcn_s_barrier();          // writes visible before next layer
}

// ---------------------------------------------------------------------------
// Fused kernel. 256 threads = 4 waves, 64 points/block, grid 4096.
// LDS ~70.7 KB -> 2 blocks/CU; VGPR ~200 (A-ring 64 + B 32 + acc 64 + misc)
// -> 2 waves/SIMD. If VGPR reports <=120, the ring collapsed again.
// ---------------------------------------------------------------------------
template <typename TI>
__global__ __launch_bounds__(256, 2) void lisa_fused_t(
    const TI* __restrict__ coord, const TI* __restrict__ latent,
    const TI* __restrict__ bias0, const TI* __restrict__ bias1,
    const TI* __restrict__ bias2, const TI* __restrict__ bias3,
    const TI* __restrict__ W4,    const TI* __restrict__ b4,
    const ushort_t* __restrict__ pw, TI* __restrict__ out,
    const int* __restrict__ flag, int want)
{
  if (*flag != want) return;
  __shared__ __align__(16) ushort_t act[2][4 * 8 * 64 * 8];  // 2 x 32 KB
  __shared__ __align__(16) float bw[4 * 256 + 256 + 1];      // biases | w4 | b4

  const int tid  = threadIdx.x;
  const int lane = tid & 63, q = lane >> 4, m15 = lane & 15;
  const int wv   = tid >> 6;                               // 0..3
  const long pbase = (long)blockIdx.x * 64 + wv * 16 + m15;

  // ---- bias/w4 table ----
  for (int i = tid; i < 1281; i += 256) {
    float v;
    if (i < 256)       v = ldv(bias0, i);
    else if (i < 512)  v = ldv(bias1, i - 256);
    else if (i < 768)  v = ldv(bias2, i - 512);
    else if (i < 1024) v = ldv(bias3, i - 768);
    else if (i < 1280) v = ldv(W4, i - 1024);
    else               v = ldv(b4, 0);
    bw[i] = v;
  }

  // ---- feature build into sigma-ordered B-frags; wave wv owns pt-tile wv ----
  {
    const long p = pbase;
    float c   = ldv(coord, p);
    float ixv = c * 2048.0f - 0.5f;
    float x0f = floorf(ixv);
    float t   = ixv - x0f;
    int   x0  = (int)x0f;
    int   i0  = imin(imax(x0, 0), NLAT - 1);
    int   i1  = imin(imax(x0 + 1, 0), NLAT - 1);
    float w0 = 1.0f - t, w1 = t;
    int rows0[3] = { imax(i0 - 1, 0), i0, imin(i0 + 1, NLAT - 1) };
    int rows1[3] = { imax(i1 - 1, 0), i1, imin(i1 + 1, NLAT - 1) };
    const TI* lat = latent + (size_t)(p >> 15) * (NLAT * DLAT);
    uint4v hu[7];
#pragma unroll
    for (int tb = 0; tb < 12; ++tb) {
      int region = tb >> 2;
      int d0 = 16 * (tb & 3) + 4 * q;
      float4 a = load4f(lat + (long)rows0[region] * DLAT + d0);
      float4 b = load4f(lat + (long)rows1[region] * DLAT + d0);
      hu[tb >> 1][(tb & 1) * 2 + 0] = pack2(w0 * a.x + w1 * b.x, w0 * a.y + w1 * b.y);
      hu[tb >> 1][(tb & 1) * 2 + 1] = pack2(w0 * a.z + w1 * b.z, w0 * a.w + w1 * b.w);
    }
    float pv[4];
#pragma unroll
    for (int s = 0; s < 4; ++s) {
      int f = 192 + 4 * q + s;
      float v = 0.0f;
      if (f == 192) v = c;
      else if (f <= 204) {
        int i = f - 193;
        float fr = (float)(1 << (i >> 1));
        float ang = c * fr;
        v = (i & 1) ? __cosf(ang) : __sinf(ang);
      }
      pv[s] = v;
    }
    hu[6][0] = pack2(pv[0], pv[1]);
    hu[6][1] = pack2(pv[2], pv[3]);
    hu[6][2] = 0; hu[6][3] = 0;

#pragma unroll
    for (int kt = 0; kt < 7; ++kt)
      *(uint4v*)&act[0][((size_t)(wv * 8 + kt) * 64 + lane) * 8] = hu[kt];
  }
  __syncthreads();   // features + bw table ready (drains ALL prior vmem -> asm
                     // vmcnt counting below starts from a clean 0)

  // ---- prologue: issue L0 kt0 -> slot 0, kt1 -> slot 1 (8 in flight) ----
  short8 Ar[4][4];
  issueA<7>(pw + PW0_OFF, Ar[0], 0, lane, wv);
  issueA<7>(pw + PW0_OFF, Ar[1], 1, lane, wv);

  float4v acc[4][4];

  run_layer_asm<7, 0, 8>(pw + PW0_OFF, pw + PW1_OFF, acc, act[0], lane, wv, Ar);
  convert_store(acc, act[1], bw + 0 * 256, lane, wv, q);
  run_layer_asm<8, 3, 8>(pw + PW1_OFF, pw + PW2_OFF, acc, act[1], lane, wv, Ar);
  convert_store(acc, act[0], bw + 1 * 256, lane, wv, q);
  run_layer_asm<8, 3, 8>(pw + PW2_OFF, pw + PW3_OFF, acc, act[0], lane, wv, Ar);
  convert_store(acc, act[1], bw + 2 * 256, lane, wv, q);
  run_layer_asm<8, 3, 0>(pw + PW3_OFF, nullptr,      acc, act[1], lane, wv, Ar);
  // last layer ends with vmwait<0> -> all asm loads retired

  // ---- final: bias3+relu fused with dot against w4 (wave covers 64 chans) ----
  float psum[4] = {0.f, 0.f, 0.f, 0.f};
#pragma unroll
  for (int m = 0; m < 4; ++m) {
    const float4 b3v = *(const float4*)&bw[3 * 256 + wv * 64 + m * 16 + 4 * q];
    const float4 w4v = *(const float4*)&bw[1024 + wv * 64 + m * 16 + 4 * q];
#pragma unroll
    for (int i = 0; i < 4; ++i) {
      float v;
      v = fmaxf(acc[m][i][0] + b3v.x, 0.f); psum[i] += v * w4v.x;
      v = fmaxf(acc[m][i][1] + b3v.y, 0.f); psum[i] += v * w4v.y;
      v = fmaxf(acc[m][i][2] + b3v.z, 0.f); psum[i] += v * w4v.z;
      v = fmaxf(acc[m][i][3] + b3v.w, 0.f); psum[i] += v * w4v.w;
    }
  }
#pragma unroll
  for (int i = 0; i < 4; ++i) {
    psum[i] += __shfl_xor(psum[i], 16, 64);
    psum[i] += __shfl_xor(psum[i], 32, 64);
  }

  // act[0] is dead (all reads retired before the L2-convert barrier) ->
  // overlay partials; slot i -> pt p=(wv+i)&3 (address-only)
  asm volatile("" ::: "memory");
  __builtin_amdgcn_s_barrier();
  float* part = (float*)act[0];      // [wv][64] partials
  if (lane < 16) {
#pragma unroll
    for (int i = 0; i < 4; ++i) {
      const int p = (wv + i) & 3;
      part[wv * 64 + p * 16 + lane] = psum[i];
    }
  }
  __syncthreads();
  if (tid < 64) {
    float s = part[tid] + part[64 + tid] + part[128 + tid] + part[192 + tid]
            + bw[1280];
    stv(out, (long)blockIdx.x * 64 + tid, s);
  }
}

extern "C" void kernel_launch(void* const* d_in, const int* in_sizes, int n_in,
                              void* d_out, int out_size, void* d_ws, size_t ws_size,
                              hipStream_t stream) {
  int* flag = (int*)d_ws;
  ushort_t* pw = (ushort_t*)d_ws + PW_BASE;

  detect_mode<<<1, 64, 0, stream>>>((const ushort_t*)d_in[1], flag);

  // fp32-input variant (flag==1)
  pack_w_t<float><<<62, 512, 0, stream>>>(
      (const float*)d_in[2], (const float*)d_in[4], (const float*)d_in[6],
      (const float*)d_in[8], pw, flag, 1);
  lisa_fused_t<float><<<4096, 256, 0, stream>>>(
      (const float*)d_in[0], (const float*)d_in[1],
      (const float*)d_in[3], (const float*)d_in[5], (const float*)d_in[7],
      (const float*)d_in[9], (const float*)d_in[10], (const float*)d_in[11],
      pw, (float*)d_out, flag, 1);

  // bf16-input variant (flag==0)
  pack_w_t<ushort_t><<<62, 512, 0, stream>>>(
      (const ushort_t*)d_in[2], (const ushort_t*)d_in[4], (const ushort_t*)d_in[6],
      (const ushort_t*)d_in[8], pw, flag, 0);
  lisa_fused_t<ushort_t><<<4096, 256, 0, stream>>>(
      (const ushort_t*)d_in[0], (const ushort_t*)d_in[1],
      (const ushort_t*)d_in[3], (const ushort_t*)d_in[5], (const ushort_t*)d_in[7],
      (const ushort_t*)d_in[9], (const ushort_t*)d_in[10], (const ushort_t*)d_in[11],
      pw, (ushort_t*)d_out, flag, 0);
}